// Round 7
// baseline (783.787 us; speedup 1.0000x reference)
//
#include <hip/hip_runtime.h>
#include <math.h>

#define Bsz    2048
#define Ccnt   100000
#define Dd     128
#define CT     128                 // classes per margin block (4 waves x 32)
#define NMBLK  782                 // ceil(Ccnt/CT); last block: only wave 0 valid
#define NCHUNK (Bsz / 32)          // 64 sample chunks of 32

typedef short  bf16x8  __attribute__((ext_vector_type(8)));
typedef float  f32x16  __attribute__((ext_vector_type(16)));
typedef float  f32x4   __attribute__((ext_vector_type(4)));

// ---- order-preserving float <-> uint encoding for atomicMax ----
static __device__ __forceinline__ unsigned int enc_f32(float f) {
    unsigned int u = __float_as_uint(f);
    return (u & 0x80000000u) ? ~u : (u | 0x80000000u);
}
static __device__ __forceinline__ float dec_f32(unsigned int u) {
    unsigned int b = (u & 0x80000000u) ? (u & 0x7fffffffu) : ~u;
    return __uint_as_float(b);
}
// fp32 -> bf16 round-to-nearest-even
static __device__ __forceinline__ unsigned short f2bf(float f) {
    unsigned int u = __float_as_uint(f);
    unsigned int r = ((u >> 16) & 1u) + 0x7fffu;
    return (unsigned short)((u + r) >> 16);
}

// Fragment packing (shared by Q and W): for a 32-row panel p, fragment t,
// lane l (0..63) holds rows p*32+(l&31), dims (l>>5)*8 + t*16 .. +8.
// pk[(p*8 + t)*64 + l] = 8 bf16. Wave-wide load of one fragment = 1KB burst.

// ---- prep1: pack Q = wnorm[labels] (bf16, fragment order); zero maxbuf ----
__global__ __launch_bounds__(256) void prep_kernel(
    const int* __restrict__ labels,
    const float* __restrict__ wnorm,
    bf16x8* __restrict__ qpk,
    unsigned int* __restrict__ maxbuf)
{
    int tid = blockIdx.x * 256 + threadIdx.x;   // 32768 threads
    if (tid < Bsz) maxbuf[tid] = 0u;            // reset running-max (enc space)
    int b   = tid >> 4;                         // sample
    int c8  = (tid & 15) << 3;                  // first of this thread's 8 dims
    if (b >= Bsz) return;
    int lab = labels[b];
    if (lab < 0) lab = 0;
    const float* src = wnorm + (size_t)lab * Dd + c8;
    float4 u = *reinterpret_cast<const float4*>(src);
    float4 v = *reinterpret_cast<const float4*>(src + 4);
    unsigned short o[8] = { f2bf(u.x), f2bf(u.y), f2bf(u.z), f2bf(u.w),
                            f2bf(v.x), f2bf(v.y), f2bf(v.z), f2bf(v.w) };
    int p = b >> 5, t = c8 >> 4, l = ((c8 >> 3) & 1) * 32 + (b & 31);
    qpk[(size_t)(p * 8 + t) * 64 + l] = *reinterpret_cast<bf16x8*>(o);
}

// ---- prep2: pack the whole W (bf16, fragment order) ----
__global__ __launch_bounds__(256) void prepw_kernel(
    const float* __restrict__ wnorm,
    bf16x8* __restrict__ wpk)
{
    int tid = blockIdx.x * 256 + threadIdx.x;   // 1.6M threads
    int c   = tid >> 4;                         // class
    int c8  = (tid & 15) << 3;
    if (c >= Ccnt) return;
    const float* src = wnorm + (size_t)c * Dd + c8;
    float4 u = *reinterpret_cast<const float4*>(src);
    float4 v = *reinterpret_cast<const float4*>(src + 4);
    unsigned short o[8] = { f2bf(u.x), f2bf(u.y), f2bf(u.z), f2bf(u.w),
                            f2bf(v.x), f2bf(v.y), f2bf(v.z), f2bf(v.w) };
    int p = c >> 5, t = c8 >> 4, l = ((c8 >> 3) & 1) * 32 + (c & 31);
    wpk[(size_t)(p * 8 + t) * 64 + l] = *reinterpret_cast<bf16x8*>(o);
}

// ---- margin max via bf16 MFMA; both operands pre-packed ----
// 4 blocks/CU (launch_bounds(256,4)): TLP hides L2 latency; no LDS, no
// barriers; per-chunk fire-and-forget global atomicMax (distinct addrs).
__global__ __launch_bounds__(256, 4) void margin_mfma_kernel(
    const int* __restrict__ labels,
    const bf16x8* __restrict__ wpk,
    const bf16x8* __restrict__ qpk,
    unsigned int* __restrict__ maxbuf)
{
    const int wave  = threadIdx.x >> 6;
    const int lane  = threadIdx.x & 63;
    const int h     = lane >> 5;
    const int lm    = lane & 31;
    const int cbase = blockIdx.x * CT + wave * 32;
    if (cbase >= Ccnt) return;          // whole-wave invalid (last block only)

    // this wave's 32 W rows as 8 A-fragments: coalesced packed loads
    const int cb = cbase >> 5;          // class-panel index
    bf16x8 afr[8];
#pragma unroll
    for (int t = 0; t < 8; ++t)
        afr[t] = wpk[(size_t)(cb * 8 + t) * 64 + lane];

    const int base_c = cbase + 4 * h;   // acc reg r -> class base_c + rowmap(r)

    for (int ch = 0; ch < NCHUNK; ++ch) {
        const int s   = ch * 32 + lm;
        const int rel = labels[s] - base_c;      // self-class relative row

        const bf16x8* qw = qpk + (size_t)ch * 8 * 64;
        bf16x8 b0 = qw[0 * 64 + lane], b1 = qw[1 * 64 + lane];
        bf16x8 b2 = qw[2 * 64 + lane], b3 = qw[3 * 64 + lane];
        bf16x8 b4 = qw[4 * 64 + lane], b5 = qw[5 * 64 + lane];
        bf16x8 b6 = qw[6 * 64 + lane], b7 = qw[7 * 64 + lane];

        f32x16 acc = {};
        acc = __builtin_amdgcn_mfma_f32_32x32x16_bf16(afr[0], b0, acc, 0, 0, 0);
        acc = __builtin_amdgcn_mfma_f32_32x32x16_bf16(afr[1], b1, acc, 0, 0, 0);
        acc = __builtin_amdgcn_mfma_f32_32x32x16_bf16(afr[2], b2, acc, 0, 0, 0);
        acc = __builtin_amdgcn_mfma_f32_32x32x16_bf16(afr[3], b3, acc, 0, 0, 0);
        acc = __builtin_amdgcn_mfma_f32_32x32x16_bf16(afr[4], b4, acc, 0, 0, 0);
        acc = __builtin_amdgcn_mfma_f32_32x32x16_bf16(afr[5], b5, acc, 0, 0, 0);
        acc = __builtin_amdgcn_mfma_f32_32x32x16_bf16(afr[6], b6, acc, 0, 0, 0);
        acc = __builtin_amdgcn_mfma_f32_32x32x16_bf16(afr[7], b7, acc, 0, 0, 0);

        // mask self-class, then max-reduce 16 regs (fmax triples -> v_max3)
        float v[16];
#pragma unroll
        for (int r = 0; r < 16; ++r) {
            const int row = (r & 3) + 8 * (r >> 2);
            v[r] = (rel == row) ? -3.0f : acc[r];
        }
        float t0 = fmaxf(fmaxf(v[0],  v[1]),  v[2]);
        float t1 = fmaxf(fmaxf(v[3],  v[4]),  v[5]);
        float t2 = fmaxf(fmaxf(v[6],  v[7]),  v[8]);
        float t3 = fmaxf(fmaxf(v[9],  v[10]), v[11]);
        float t4 = fmaxf(fmaxf(v[12], v[13]), v[14]);
        float m  = fmaxf(fmaxf(fmaxf(t0, t1), t2),
                         fmaxf(fmaxf(t3, t4), v[15]));
        m = fmaxf(m, __shfl_xor(m, 32));    // join the two k-half lane sets
        if (lane < 32) atomicMax(&maxbuf[s], enc_f32(m));
    }
}

// ---- elementwise scale: out = logits * 64 (nontemporal, x2 unroll) ----
__global__ __launch_bounds__(256) void scale_kernel(
    const f32x4* __restrict__ in, f32x4* __restrict__ out, int n4)
{
    int i0     = (blockIdx.x * 256 + threadIdx.x) * 2;
    int stride = gridDim.x * 512;
    for (int i = i0; i < n4; i += stride) {
        f32x4 a = __builtin_nontemporal_load(in + i);
        f32x4 b = __builtin_nontemporal_load(in + i + 1);   // n4 is even
        a *= 64.f;
        b *= 64.f;
        __builtin_nontemporal_store(a, out + i);
        __builtin_nontemporal_store(b, out + i + 1);
    }
}

// ---- per-sample target fixup ----
__global__ void fixup_kernel(const float* __restrict__ logits,
                             const int* __restrict__ labels,
                             const unsigned int* __restrict__ maxbuf,
                             float* __restrict__ out)
{
    int b = blockIdx.x * blockDim.x + threadIdx.x;
    if (b >= Bsz) return;
    int lab = labels[b];
    if (lab < 0) return;
    float mx = dec_f32(maxbuf[b]);
    mx = fminf(fmaxf(mx, -1.f), 1.f);
    float theta  = acosf(mx);
    float d      = theta - 1.0f;                                 // K1
    float smooth = 0.012f / powf(1.0f + fabsf(d) * 20.0f, 1.1f); // 0.03*K3
    float margin = fmaxf(d, 0.f) * 0.1f + 0.4f + smooth;         // K2, K3
    size_t off = (size_t)b * Ccnt + lab;
    float x = logits[off];
    out[off] = cosf(acosf(x) + margin) * 64.0f;                  // S
}

extern "C" void kernel_launch(void* const* d_in, const int* in_sizes, int n_in,
                              void* d_out, int out_size, void* d_ws, size_t ws_size,
                              hipStream_t stream)
{
    const float* logits = (const float*)d_in[0];
    const int*   labels = (const int*)d_in[1];
    const float* wnorm  = (const float*)d_in[2];
    float* out = (float*)d_out;

    unsigned int* maxbuf = (unsigned int*)d_ws;                    // 8 KB
    bf16x8*       qpk    = (bf16x8*)((char*)d_ws + 8192);          // 512 KB
    bf16x8*       wpk    = (bf16x8*)((char*)d_ws + 8192 + 524288); // 25.6 MB

    prep_kernel<<<(Bsz * (Dd / 8) + 255) / 256, 256, 0, stream>>>(
        labels, wnorm, qpk, maxbuf);

    prepw_kernel<<<(Ccnt * (Dd / 8) + 255) / 256, 256, 0, stream>>>(
        wnorm, wpk);

    margin_mfma_kernel<<<NMBLK, 256, 0, stream>>>(
        labels, wpk, qpk, maxbuf);

    int n4 = Bsz * (Ccnt / 4);
    scale_kernel<<<2048, 256, 0, stream>>>(
        (const f32x4*)logits, (f32x4*)out, n4);

    fixup_kernel<<<(Bsz + 255) / 256, 256, 0, stream>>>(
        logits, labels, maxbuf, out);
}

// Round 8
// 470.349 us; speedup vs baseline: 1.6664x; 1.6664x over previous
//
#include <hip/hip_runtime.h>
#include <math.h>

#define Bsz    2048
#define Ccnt   100000
#define Dd     128
#define CT     128                 // classes per margin block (4 waves x 32)
#define NMBLK  782                 // ceil(Ccnt/CT); 100000%32==0 -> no partial wave
#define NCHUNK (Bsz / 32)          // 64 sample chunks of 32

typedef short  bf16x8  __attribute__((ext_vector_type(8)));
typedef float  f32x16  __attribute__((ext_vector_type(16)));
typedef float  f32x4   __attribute__((ext_vector_type(4)));

// ---- order-preserving float <-> uint encoding for atomicMax ----
static __device__ __forceinline__ unsigned int enc_f32(float f) {
    unsigned int u = __float_as_uint(f);
    return (u & 0x80000000u) ? ~u : (u | 0x80000000u);
}
static __device__ __forceinline__ float dec_f32(unsigned int u) {
    unsigned int b = (u & 0x80000000u) ? (u & 0x7fffffffu) : ~u;
    return __uint_as_float(b);
}
// fp32 -> bf16 round-to-nearest-even
static __device__ __forceinline__ unsigned short f2bf(float f) {
    unsigned int u = __float_as_uint(f);
    unsigned int r = ((u >> 16) & 1u) + 0x7fffu;
    return (unsigned short)((u + r) >> 16);
}

// ---- prep: pack Q = wnorm[labels] as bf16 in MFMA B-fragment order.
// Chunk ch occupies qpk[ch*512 .. ch*512+511]; element t*64+l holds
// Q[s = ch*32 + (l&31)][d = (l>>5)*8 + t*16 .. +8]. Also zero maxbuf.
__global__ __launch_bounds__(256) void prep_kernel(
    const int* __restrict__ labels,
    const float* __restrict__ wnorm,
    bf16x8* __restrict__ qpk,
    unsigned int* __restrict__ maxbuf)
{
    int tid = blockIdx.x * 256 + threadIdx.x;   // 32768 threads
    if (tid < Bsz) maxbuf[tid] = 0u;            // reset running-max (enc space)
    int b   = tid >> 4;                         // sample
    int c8  = (tid & 15) << 3;                  // first of this thread's 8 dims
    if (b >= Bsz) return;
    int lab = labels[b];
    if (lab < 0) lab = 0;
    const float* src = wnorm + (size_t)lab * Dd + c8;
    float4 u = *reinterpret_cast<const float4*>(src);
    float4 v = *reinterpret_cast<const float4*>(src + 4);
    unsigned short o[8] = { f2bf(u.x), f2bf(u.y), f2bf(u.z), f2bf(u.w),
                            f2bf(v.x), f2bf(v.y), f2bf(v.z), f2bf(v.w) };
    int p = b >> 5, t = c8 >> 4, l = ((c8 >> 3) & 1) * 32 + (b & 31);
    qpk[(size_t)(p * 8 + t) * 64 + l] = *reinterpret_cast<bf16x8*>(o);
}

// ---- margin chunks: B-fragments LDS-staged ONCE per block, shared by all
// 4 waves (4x L2 traffic cut). T14 split: issue ch+1 global loads before
// compute of ch, ds_write after, 1 barrier/chunk, double-buffered.
template<bool EDGE>
__device__ __forceinline__ void margin_chunks(
    const int* __restrict__ labels,
    const bf16x8* __restrict__ qpk,
    const bf16x8 (&afr)[8], int base_c, int lane, int tid,
    unsigned int* smax, bf16x8 (*qs)[512])
{
    const int lm  = lane & 31;
    const int lim = Ccnt - base_c;   // used only when EDGE

    // prologue: stage chunk 0 (8KB: 2 x 16B per thread)
    qs[0][tid]       = qpk[tid];
    qs[0][256 + tid] = qpk[256 + tid];
    __syncthreads();

    for (int ch = 0; ch < NCHUNK; ++ch) {
        const int buf = ch & 1;

        // issue next chunk's global loads (in flight during compute)
        bf16x8 s0, s1;
        if (ch + 1 < NCHUNK) {
            s0 = qpk[(ch + 1) * 512 + tid];
            s1 = qpk[(ch + 1) * 512 + 256 + tid];
        }

        const int s   = ch * 32 + lm;
        const int rel = labels[s] - base_c;      // self-class relative row

        bf16x8 b0 = qs[buf][0 * 64 + lane], b1 = qs[buf][1 * 64 + lane];
        bf16x8 b2 = qs[buf][2 * 64 + lane], b3 = qs[buf][3 * 64 + lane];
        bf16x8 b4 = qs[buf][4 * 64 + lane], b5 = qs[buf][5 * 64 + lane];
        bf16x8 b6 = qs[buf][6 * 64 + lane], b7 = qs[buf][7 * 64 + lane];

        f32x16 a0 = {}, a1 = {};   // two independent K-chains
        a0 = __builtin_amdgcn_mfma_f32_32x32x16_bf16(afr[0], b0, a0, 0, 0, 0);
        a1 = __builtin_amdgcn_mfma_f32_32x32x16_bf16(afr[1], b1, a1, 0, 0, 0);
        a0 = __builtin_amdgcn_mfma_f32_32x32x16_bf16(afr[2], b2, a0, 0, 0, 0);
        a1 = __builtin_amdgcn_mfma_f32_32x32x16_bf16(afr[3], b3, a1, 0, 0, 0);
        a0 = __builtin_amdgcn_mfma_f32_32x32x16_bf16(afr[4], b4, a0, 0, 0, 0);
        a1 = __builtin_amdgcn_mfma_f32_32x32x16_bf16(afr[5], b5, a1, 0, 0, 0);
        a0 = __builtin_amdgcn_mfma_f32_32x32x16_bf16(afr[6], b6, a0, 0, 0, 0);
        a1 = __builtin_amdgcn_mfma_f32_32x32x16_bf16(afr[7], b7, a1, 0, 0, 0);

        // mask self-class (+OOB rows for the edge block), max-reduce 16 regs
        float v[16];
#pragma unroll
        for (int r = 0; r < 16; ++r) {
            const int row = (r & 3) + 8 * (r >> 2);  // +4h folded into base_c
            float tv = a0[r] + a1[r];
            bool kill = (rel == row);
            if (EDGE) kill = kill || (row >= lim);
            v[r] = kill ? -3.0f : tv;
        }
        float t0 = fmaxf(fmaxf(v[0],  v[1]),  v[2]);
        float t1 = fmaxf(fmaxf(v[3],  v[4]),  v[5]);
        float t2 = fmaxf(fmaxf(v[6],  v[7]),  v[8]);
        float t3 = fmaxf(fmaxf(v[9],  v[10]), v[11]);
        float t4 = fmaxf(fmaxf(v[12], v[13]), v[14]);
        float m  = fmaxf(fmaxf(fmaxf(t0, t1), t2),
                         fmaxf(fmaxf(t3, t4), v[15]));
        m = fmaxf(m, __shfl_xor(m, 32));    // join the two K-half lane sets
        if (lane < 32) atomicMax(&smax[s], enc_f32(m));

        // write staged data for ch+1 into the other buffer
        if (ch + 1 < NCHUNK) {
            qs[buf ^ 1][tid]       = s0;
            qs[buf ^ 1][256 + tid] = s1;
        }
        __syncthreads();
    }
}

__global__ __launch_bounds__(256, 3) void margin_mfma_kernel(
    const int* __restrict__ labels,
    const float* __restrict__ wnorm,
    const bf16x8* __restrict__ qpk,
    unsigned int* __restrict__ maxbuf)
{
    __shared__ unsigned int smax[Bsz];          // 8 KB
    __shared__ bf16x8 qs[2][512];               // 2 x 8 KB staging
    for (int i = threadIdx.x; i < Bsz; i += 256) smax[i] = 0u;
    // (covered by the prologue barrier inside margin_chunks)

    const int tid   = threadIdx.x;
    const int wave  = tid >> 6;
    const int lane  = tid & 63;
    const int h     = lane >> 5;
    const int lm    = lane & 31;
    const int cbase = blockIdx.x * CT + wave * 32;
    const int cls   = cbase + lm;
    const bool cvalid = cls < Ccnt;

    // this lane's W row as 8 A-fragments (fp32 load + convert, held all kernel)
    bf16x8 afr[8];
    {
        const float* wr = wnorm + (size_t)(cvalid ? cls : 0) * Dd + h * 8;
#pragma unroll
        for (int t = 0; t < 8; ++t) {
            float4 u = *reinterpret_cast<const float4*>(wr + t * 16);
            float4 v = *reinterpret_cast<const float4*>(wr + t * 16 + 4);
            unsigned short o[8] = { f2bf(u.x), f2bf(u.y), f2bf(u.z), f2bf(u.w),
                                    f2bf(v.x), f2bf(v.y), f2bf(v.z), f2bf(v.w) };
            afr[t] = *reinterpret_cast<bf16x8*>(o);
        }
    }
    const int base_c = cbase + 4 * h;

    if (blockIdx.x == NMBLK - 1)
        margin_chunks<true >(labels, qpk, afr, base_c, lane, tid, smax, qs);
    else
        margin_chunks<false>(labels, qpk, afr, base_c, lane, tid, smax, qs);

    // last in-loop barrier already ordered the final atomics
    for (int i = threadIdx.x; i < Bsz; i += 256)
        atomicMax(&maxbuf[i], smax[i]);
}

// ---- elementwise scale: out = logits * 64 (nontemporal, x2 unroll) ----
__global__ __launch_bounds__(256) void scale_kernel(
    const f32x4* __restrict__ in, f32x4* __restrict__ out, int n4)
{
    int i0     = (blockIdx.x * 256 + threadIdx.x) * 2;
    int stride = gridDim.x * 512;
    for (int i = i0; i < n4; i += stride) {
        f32x4 a = __builtin_nontemporal_load(in + i);
        f32x4 b = __builtin_nontemporal_load(in + i + 1);   // n4 is even
        a *= 64.f;
        b *= 64.f;
        __builtin_nontemporal_store(a, out + i);
        __builtin_nontemporal_store(b, out + i + 1);
    }
}

// ---- per-sample target fixup ----
__global__ void fixup_kernel(const float* __restrict__ logits,
                             const int* __restrict__ labels,
                             const unsigned int* __restrict__ maxbuf,
                             float* __restrict__ out)
{
    int b = blockIdx.x * blockDim.x + threadIdx.x;
    if (b >= Bsz) return;
    int lab = labels[b];
    if (lab < 0) return;
    float mx = dec_f32(maxbuf[b]);
    mx = fminf(fmaxf(mx, -1.f), 1.f);
    float theta  = acosf(mx);
    float d      = theta - 1.0f;                                 // K1
    float smooth = 0.012f / powf(1.0f + fabsf(d) * 20.0f, 1.1f); // 0.03*K3
    float margin = fmaxf(d, 0.f) * 0.1f + 0.4f + smooth;         // K2, K3
    size_t off = (size_t)b * Ccnt + lab;
    float x = logits[off];
    out[off] = cosf(acosf(x) + margin) * 64.0f;                  // S
}

extern "C" void kernel_launch(void* const* d_in, const int* in_sizes, int n_in,
                              void* d_out, int out_size, void* d_ws, size_t ws_size,
                              hipStream_t stream)
{
    const float* logits = (const float*)d_in[0];
    const int*   labels = (const int*)d_in[1];
    const float* wnorm  = (const float*)d_in[2];
    float* out = (float*)d_out;

    unsigned int* maxbuf = (unsigned int*)d_ws;                 // 8 KB
    bf16x8*       qpk    = (bf16x8*)((char*)d_ws + 8192);       // 512 KB

    prep_kernel<<<(Bsz * (Dd / 8) + 255) / 256, 256, 0, stream>>>(
        labels, wnorm, qpk, maxbuf);

    margin_mfma_kernel<<<NMBLK, 256, 0, stream>>>(
        labels, wnorm, qpk, maxbuf);

    int n4 = Bsz * (Ccnt / 4);
    scale_kernel<<<2048, 256, 0, stream>>>(
        (const f32x4*)logits, (f32x4*)out, n4);

    fixup_kernel<<<(Bsz + 255) / 256, 256, 0, stream>>>(
        logits, labels, maxbuf, out);
}